// Round 10
// baseline (637.024 us; speedup 1.0000x reference)
//
#include <hip/hip_runtime.h>

#define WROW 52   // 13 time slices * 4 feats per node
#define TG 8      // targets per k_edge block (1024 blocks -> 4 blocks/CU)

typedef _Float16 half_t;
typedef _Float16 half8 __attribute__((ext_vector_type(8)));
typedef float f32x4 __attribute__((ext_vector_type(4)));

#define SC 0.0009765625f   // 2^-10 activation pre-scale (exact power of 2)

// pack two f32 -> two f16 (RTZ) as a 32-bit word
__device__ __forceinline__ unsigned pkrtz(float a, float b) {
  auto v = __builtin_amdgcn_cvt_pkrtz(a, b);   // __fp16 x2
  return *(unsigned*)&v;
}

// ---------------- conv (2 layers) + edge-input projection -------------------
// LANES threads per node. cp: per-node scratch 160 floats.
// an/bn are stored PRE-SCALED by SC.
template<int LANES>
__device__ __forceinline__ void conv_proj(
    int lane, int gid, float* cp,
    const float* __restrict__ cw1, const float* __restrict__ cb1,
    const float* __restrict__ cw2, const float* __restrict__ cb2,
    const float* __restrict__ ew1,
    float* __restrict__ an, float* __restrict__ bn)
{
  #pragma unroll
  for (int o = 0; o < 96 / LANES; ++o) {
    int idx = lane + o * LANES;
    int tt = idx >> 5, f = idx & 31;
    float a = cb1[f];
    #pragma unroll
    for (int kt = 0; kt < 3; ++kt)
      #pragma unroll
      for (int d = 0; d < 4; ++d)
        a = fmaf(cp[(tt + kt) * 4 + d], cw1[(kt * 4 + d) * 32 + f], a);
    cp[32 + idx] = fmaxf(a, 0.f);
  }
  __syncthreads();
  #pragma unroll
  for (int o = 0; o < 32 / LANES; ++o) {
    int f = lane + o * LANES;
    float a = cb2[f];
    #pragma unroll
    for (int kt = 0; kt < 3; ++kt)
      for (int f1 = 0; f1 < 32; ++f1)
        a = fmaf(cp[32 + kt * 32 + f1], cw2[(kt * 32 + f1) * 32 + f], a);
    cp[128 + f] = fmaxf(a, 0.f);
  }
  __syncthreads();
  #pragma unroll
  for (int o = 0; o < 128 / LANES; ++o) {
    int j = lane + o * LANES;
    float a = 0.f, bb = 0.f;
    for (int f = 0; f < 32; ++f) {
      float h = cp[128 + f];
      a  = fmaf(h, ew1[f * 128 + j], a);
      bb = fmaf(h, ew1[(32 + f) * 128 + j], bb);
    }
    an[gid * 128 + j] = a * SC;
    bn[gid * 128 + j] = bb * SC;
  }
}

// ---------------- k_init: transpose + step-0 conv/proj ---------------------
__global__ __launch_bounds__(256) void k_init(
    const float* __restrict__ ts,
    const float* __restrict__ cw1, const float* __restrict__ cb1,
    const float* __restrict__ cw2, const float* __restrict__ cb2,
    const float* __restrict__ ew1,
    float* __restrict__ win, float* __restrict__ an, float* __restrict__ bn)
{
  __shared__ float cp[16 * 160];
  int blk = blockIdx.x;
  int b = blk >> 2, n0 = (blk & 3) << 4;
  int tid = threadIdx.x;
  int ln = tid >> 4, lane = tid & 15;
  int n = n0 + ln;
  int gid = b * 64 + n;
  float* mycp = cp + ln * 160;
  for (int idx = lane; idx < 20; idx += 16) {
    int tt = idx >> 2, d = idx & 3;
    float v = ts[((b * 5 + tt) * 64 + n) * 4 + d];
    mycp[idx] = v;
    win[gid * WROW + idx] = v;
  }
  __syncthreads();
  conv_proj<16>(lane, gid, mycp, cw1, cb1, cw2, cb2, ew1, an, bn);
}

// ---------------- k_wsplit: 5 weight mats -> f16 hi/lo B-fragment layout ---
// mat 0: ew2, 1: nw1, 2: nw2, 3: dw1[4:132], 4: dw2. dst = base (10x16384 halves)
__global__ __launch_bounds__(256) void k_wsplit(
    const float* __restrict__ ew2, const float* __restrict__ nw1,
    const float* __restrict__ nw2, const float* __restrict__ dw1,
    const float* __restrict__ dw2, half_t* __restrict__ dst)
{
  int mat = blockIdx.x >> 6;
  const float* src = (mat == 0) ? ew2 : (mat == 1) ? nw1 : (mat == 2) ? nw2
                   : (mat == 3) ? (dw1 + 512) : dw2;
  half_t* dh = dst + mat * 2 * 16384;
  half_t* dl = dh + 16384;
  int g = (blockIdx.x & 63) * 256 + threadIdx.x;   // k*128+col
  int k = g >> 7, col = g & 127;
  float x = src[g];
  _Float16 hi = (_Float16)x;
  float lo = x - (float)hi;
  int c = col >> 4, kb = k >> 5, kk = k & 31;
  int lane = ((kk >> 3) << 4) | (col & 15);
  int j = kk & 7;
  int idx = ((c * 4 + kb) * 64 + lane) * 8 + j;
  dh[idx] = hi;
  dl[idx] = (_Float16)lo;
}

// ---------------- k_edge_v7: single-buffer, high-occupancy -----------------
// TG=8, 1024 blocks, 36 KB LDS, VGPR<=128 -> 4 blocks/CU (16 waves).
// Cross-block wave overlap saturates the LDS port (the measured bottleneck).
// C = 1024 * (Ah@Bh + Ah@Bl + Al@Bh), A = relu(anS + btS)  (pre-scaled 2^-10)
__global__ __launch_bounds__(256, 4) void k_edge_v7(
    const float* __restrict__ an, const float* __restrict__ bn,
    const float* __restrict__ eb1, const float* __restrict__ eb2,
    const half_t* __restrict__ Bh, const half_t* __restrict__ Bl,
    float* __restrict__ nm)
{
  __shared__ __align__(16) half_t sAh[8192];   // 16 KB
  __shared__ __align__(16) half_t sAl[8192];   // 16 KB
  __shared__ float s_bt[TG * 128];             // 4 KB
  int blk = blockIdx.x;
  int b = blk & 127, t0 = (blk >> 7) * TG;  // same-b groups spread over rounds
  int tid = threadIdx.x;
  int w = tid >> 6, lane = tid & 63;

  // ---- stage bt rows (+eb1*SC) into LDS (coalesced) ----
  #pragma unroll
  for (int i = 0; i < TG * 128 / 256; ++i) {
    int idx = tid + (i << 8);
    int tt = idx >> 7, j = idx & 127;
    s_bt[idx] = bn[((b << 6) + t0 + tt) * 128 + j] + eb1[j] * SC;
  }

  // ---- this thread's an slice in registers: rows it*16+(tid&15), kb8=tid>>4
  float au[4][8];
  {
    int kb8 = tid >> 4, sl = tid & 15;
    #pragma unroll
    for (int it = 0; it < 4; ++it) {
      const float* ap = an + (b << 13) + ((it * 16 + sl) << 7) + (kb8 << 3);
      float4 x0 = *(const float4*)ap;
      float4 x1 = *(const float4*)(ap + 4);
      au[it][0] = x0.x; au[it][1] = x0.y; au[it][2] = x0.z; au[it][3] = x0.w;
      au[it][4] = x1.x; au[it][5] = x1.y; au[it][6] = x1.z; au[it][7] = x1.w;
    }
  }

  // ---- B fragments in registers (tt-invariant): cols (w*2+cc)*16.. ----
  half8 rbh[2][4], rbl[2][4];
  #pragma unroll
  for (int cc = 0; cc < 2; ++cc)
    #pragma unroll
    for (int kb = 0; kb < 4; ++kb) {
      int c = w * 2 + cc;
      rbh[cc][kb] = *(const half8*)(Bh + ((c * 4 + kb) * 64 + lane) * 8);
      rbl[cc][kb] = *(const half8*)(Bl + ((c * 4 + kb) * 64 + lane) * 8);
    }

  float bias0 = eb2[(w * 2 + 0) * 16 + (lane & 15)];
  float bias1 = eb2[(w * 2 + 1) * 16 + (lane & 15)];
  int rowoff = (lane >> 4) * 4;

  __syncthreads();                 // s_bt ready

  for (int tt = 0; tt < TG; ++tt) {
    // ---- split(tt): relu(au + bt) -> f16 hi/lo fragments (write-linear) ----
    {
      const float* bp = s_bt + (tt << 7) + ((tid >> 4) << 3);
      float4 b0 = *(const float4*)bp;
      float4 b1 = *(const float4*)(bp + 4);
      float bs[8] = {b0.x, b0.y, b0.z, b0.w, b1.x, b1.y, b1.z, b1.w};
      #pragma unroll
      for (int it = 0; it < 4; ++it) {
        int u = tid + (it << 8);
        float h32[8], l32[8];
        #pragma unroll
        for (int i = 0; i < 8; ++i) {
          float x = fmaxf(au[it][i] + bs[i], 0.f);
          float h = __uint_as_float(__float_as_uint(x) & 0xffffe000u);
          h32[i] = h;
          l32[i] = x - h;
        }
        unsigned hw[4], lw[4];
        #pragma unroll
        for (int p = 0; p < 4; ++p) {
          hw[p] = pkrtz(h32[2 * p], h32[2 * p + 1]);
          lw[p] = pkrtz(l32[2 * p], l32[2 * p + 1]);
        }
        *(uint4*)(sAh + u * 8) = make_uint4(hw[0], hw[1], hw[2], hw[3]);
        *(uint4*)(sAl + u * 8) = make_uint4(lw[0], lw[1], lw[2], lw[3]);
      }
    }
    __syncthreads();               // fragments ready

    f32x4 acc[4][2];
    #pragma unroll
    for (int rr = 0; rr < 4; ++rr)
      #pragma unroll
      for (int cc = 0; cc < 2; ++cc)
        acc[rr][cc] = (f32x4){0.f, 0.f, 0.f, 0.f};

    #pragma unroll
    for (int kb = 0; kb < 4; ++kb) {
      half8 ah[4], al[4];
      #pragma unroll
      for (int rr = 0; rr < 4; ++rr) {
        ah[rr] = *(const half8*)(sAh + ((rr * 4 + kb) * 64 + lane) * 8);
        al[rr] = *(const half8*)(sAl + ((rr * 4 + kb) * 64 + lane) * 8);
      }
      #pragma unroll
      for (int cc = 0; cc < 2; ++cc)
        #pragma unroll
        for (int rr = 0; rr < 4; ++rr) {
          acc[rr][cc] = __builtin_amdgcn_mfma_f32_16x16x32_f16(ah[rr], rbh[cc][kb], acc[rr][cc], 0, 0, 0);
          acc[rr][cc] = __builtin_amdgcn_mfma_f32_16x16x32_f16(ah[rr], rbl[cc][kb], acc[rr][cc], 0, 0, 0);
          acc[rr][cc] = __builtin_amdgcn_mfma_f32_16x16x32_f16(al[rr], rbh[cc][kb], acc[rr][cc], 0, 0, 0);
        }
    }

    // epilogue: bias+relu, mask s==t, in-wave row reduction, coalesced store
    int t = t0 + tt;
    float csum0 = 0.f, csum1 = 0.f;
    #pragma unroll
    for (int rr = 0; rr < 4; ++rr) {
      int sbase = rr * 16 + rowoff;
      #pragma unroll
      for (int q = 0; q < 4; ++q) {
        int s = sbase + q;
        float y0 = acc[rr][0][q] * 1024.f + bias0;
        float y1 = acc[rr][1][q] * 1024.f + bias1;
        if (s != t) {
          csum0 += fmaxf(y0, 0.f);
          csum1 += fmaxf(y1, 0.f);
        }
      }
    }
    csum0 += __shfl_xor(csum0, 16, 64);
    csum0 += __shfl_xor(csum0, 32, 64);
    csum1 += __shfl_xor(csum1, 16, 64);
    csum1 += __shfl_xor(csum1, 32, 64);
    if (lane < 32)
      nm[((b << 6) + t) * 128 + w * 32 + lane] = (lane < 16) ? csum0 : csum1;
    __syncthreads();               // all reads of sA done before next split
  }
}

// ---------------- k_nd_mfma: node MLP + decoder via MFMA + head + conv -----
// 16 nodes/block, 512 blocks. 4 layers of [16x128]@[128x128] on matrix pipe.
__global__ __launch_bounds__(256) void k_nd_mfma(
    int step,
    const float* __restrict__ nm,
    const half_t* __restrict__ wsp,   // split weights base (Bh); mats 1..4 used
    const float* __restrict__ nb1, const float* __restrict__ nb2,
    const float* __restrict__ dw1, const float* __restrict__ db1,
    const float* __restrict__ db2,
    const float* __restrict__ ow,  const float* __restrict__ ob,
    const float* __restrict__ cw1, const float* __restrict__ cb1,
    const float* __restrict__ cw2, const float* __restrict__ cb2,
    const float* __restrict__ ew1,
    float* __restrict__ win, float* __restrict__ an, float* __restrict__ bn,
    float* __restrict__ out)
{
  __shared__ __align__(16) float Xraw[16][132];
  __shared__ __align__(16) half_t sAh[2048];
  __shared__ __align__(16) half_t sAl[2048];
  __shared__ float sP[16][4];
  __shared__ float s_dw1a[4 * 128];
  __shared__ float s_nxt[16][4];
  __shared__ float cp[16 * 160];

  int blk = blockIdx.x;
  int b = blk >> 2, n0 = (blk & 3) << 4;
  int tid = threadIdx.x;
  int w = tid >> 6, lane = tid & 63;

  // stage X = nm rows (coalesced float4), P, dw1 first 4 rows
  #pragma unroll
  for (int i = 0; i < 2; ++i) {
    int idx = tid + (i << 8);              // 512 float4s
    int row = idx >> 5, jf = idx & 31;
    *(float4*)&Xraw[row][jf << 2] =
        *(const float4*)(nm + ((b * 64 + n0 + row) << 7) + (jf << 2));
  }
  if (tid < 64) {
    int ln = tid >> 2, d = tid & 3;
    sP[ln][d] = win[(b * 64 + n0 + ln) * WROW + (step + 4) * 4 + d];
  }
  for (int idx = tid; idx < 512; idx += 256) s_dw1a[idx] = dw1[idx];
  __syncthreads();

  // split Xraw (scaled by SC) -> A-fragments, write-linear
  auto splitX = [&]() {
    int kb = tid >> 6, l = tid & 63;
    int row = l & 15, k0 = (kb << 5) + ((l >> 4) << 3);
    float h32[8], l32[8];
    #pragma unroll
    for (int i = 0; i < 8; ++i) {
      float x = Xraw[row][k0 + i] * SC;
      float h = __uint_as_float(__float_as_uint(x) & 0xffffe000u);
      h32[i] = h;
      l32[i] = x - h;
    }
    unsigned hw[4], lw[4];
    #pragma unroll
    for (int p = 0; p < 4; ++p) {
      hw[p] = pkrtz(h32[2 * p], h32[2 * p + 1]);
      lw[p] = pkrtz(l32[2 * p], l32[2 * p + 1]);
    }
    *(uint4*)(sAh + tid * 8) = make_uint4(hw[0], hw[1], hw[2], hw[3]);
    *(uint4*)(sAl + tid * 8) = make_uint4(lw[0], lw[1], lw[2], lw[3]);
  };

  // one dense layer: Xraw <- relu(Xraw @ W + bias [+ P@dw1a]), via MFMA
  auto layerM = [&](const half_t* Wh, const half_t* Wl,
                    const float* bias, bool withP) {
    splitX();
    __syncthreads();
    #pragma unroll
    for (int cc = 0; cc < 2; ++cc) {
      int c = w * 2 + cc;
      int col = c * 16 + (lane & 15);
      int row0 = (lane >> 4) * 4;
      float bj = bias[col];
      f32x4 acc;
      #pragma unroll
      for (int q = 0; q < 4; ++q) {
        float v = bj;
        if (withP) {
          #pragma unroll
          for (int d = 0; d < 4; ++d)
            v = fmaf(sP[row0 + q][d], s_dw1a[d * 128 + col], v);
        }
        acc[q] = v * SC;
      }
      #pragma unroll
      for (int kb = 0; kb < 4; ++kb) {
        half8 ah = *(const half8*)(sAh + ((kb << 6) + lane) * 8);
        half8 al = *(const half8*)(sAl + ((kb << 6) + lane) * 8);
        half8 bh = *(const half8*)(Wh + ((c * 4 + kb) * 64 + lane) * 8);
        half8 bl = *(const half8*)(Wl + ((c * 4 + kb) * 64 + lane) * 8);
        acc = __builtin_amdgcn_mfma_f32_16x16x32_f16(ah, bh, acc, 0, 0, 0);
        acc = __builtin_amdgcn_mfma_f32_16x16x32_f16(ah, bl, acc, 0, 0, 0);
        acc = __builtin_amdgcn_mfma_f32_16x16x32_f16(al, bh, acc, 0, 0, 0);
      }
      #pragma unroll
      for (int q = 0; q < 4; ++q)
        Xraw[row0 + q][col] = fmaxf(acc[q] * 1024.f, 0.f);
    }
    __syncthreads();
  };

  const half_t* nh1 = wsp + 2 * 16384;  const half_t* nl1 = nh1 + 16384;
  const half_t* nh2 = wsp + 4 * 16384;  const half_t* nl2 = nh2 + 16384;
  const half_t* dh1 = wsp + 6 * 16384;  const half_t* dl1 = dh1 + 16384;
  const half_t* dh2 = wsp + 8 * 16384;  const half_t* dl2 = dh2 + 16384;

  layerM(nh1, nl1, nb1, false);   // node mlp 1
  layerM(nh2, nl2, nb2, false);   // node mlp 2
  layerM(dh1, dl1, db1, true);    // dec 1 (P part via dw1 rows 0..3)
  layerM(dh2, dl2, db2, false);   // dec 2

  // output head: nxt = X @ ow + ob + prev  (k split 4-ways + shfl reduce)
  {
    int ln = tid >> 4, d = (tid >> 2) & 3, kq = tid & 3;
    float cs = 0.f;
    #pragma unroll
    for (int i = 0; i < 32; ++i) {
      int k = (kq << 5) + i;
      cs = fmaf(Xraw[ln][k], ow[k * 4 + d], cs);
    }
    cs += __shfl_xor(cs, 1, 64);
    cs += __shfl_xor(cs, 2, 64);
    if ((tid & 3) == 0) {
      float a = cs + ob[d] + sP[ln][d];
      int n = n0 + ln, gid = b * 64 + n;
      win[gid * WROW + (step + 5) * 4 + d] = a;
      out[((b * 8 + step) * 64 + n) * 4 + d] = a;
      s_nxt[ln][d] = a;
    }
  }
  __syncthreads();

  if (step < 7) {
    int ln = tid >> 4, lane2 = tid & 15;
    int gid = b * 64 + n0 + ln;
    float* mycp = cp + ln * 160;
    mycp[lane2] = win[gid * WROW + (step + 1) * 4 + lane2];
    if (lane2 < 4) mycp[16 + lane2] = s_nxt[ln][lane2];
    __syncthreads();
    conv_proj<16>(lane2, gid, mycp, cw1, cb1, cw2, cb2, ew1, an, bn);
  }
}

extern "C" void kernel_launch(void* const* d_in, const int* in_sizes, int n_in,
                              void* d_out, int out_size, void* d_ws, size_t ws_size,
                              hipStream_t stream) {
  (void)in_sizes; (void)n_in; (void)out_size; (void)ws_size;
  const float* ts  = (const float*)d_in[0];
  const float* cw1 = (const float*)d_in[1];
  const float* cb1 = (const float*)d_in[2];
  const float* cw2 = (const float*)d_in[3];
  const float* cb2 = (const float*)d_in[4];
  const float* ew1 = (const float*)d_in[5];
  const float* eb1 = (const float*)d_in[6];
  const float* ew2 = (const float*)d_in[7];
  const float* eb2 = (const float*)d_in[8];
  const float* nw1 = (const float*)d_in[9];
  const float* nb1 = (const float*)d_in[10];
  const float* nw2 = (const float*)d_in[11];
  const float* nb2 = (const float*)d_in[12];
  const float* dw1 = (const float*)d_in[13];
  const float* db1 = (const float*)d_in[14];
  const float* dw2 = (const float*)d_in[15];
  const float* db2 = (const float*)d_in[16];
  const float* ow  = (const float*)d_in[17];
  const float* ob  = (const float*)d_in[18];
  float* out = (float*)d_out;
  float* ws  = (float*)d_ws;
  float* win = ws;                        // 425984 floats
  float* an  = win + 425984;              // 1048576
  float* bn  = an + 1048576;              // 1048576
  float* nmb = bn + 1048576;              // 1048576
  half_t* wsp = (half_t*)(nmb + 1048576); // 10 x 16384 halves (Bh,Bl,Nh1,...)
  half_t* Bh = wsp;
  half_t* Bl = Bh + 16384;

  hipLaunchKernelGGL(k_wsplit, dim3(320), dim3(256), 0, stream,
                     ew2, nw1, nw2, dw1, dw2, wsp);
  hipLaunchKernelGGL(k_init, dim3(512), dim3(256), 0, stream,
                     ts, cw1, cb1, cw2, cb2, ew1, win, an, bn);
  for (int k = 0; k < 8; ++k) {
    hipLaunchKernelGGL(k_edge_v7, dim3(1024), dim3(256), 0, stream,
                       an, bn, eb1, eb2, Bh, Bl, nmb);
    hipLaunchKernelGGL(k_nd_mfma, dim3(512), dim3(256), 0, stream,
                       k, nmb, wsp, nb1, nb2, dw1, db1, db2,
                       ow, ob, cw1, cb1, cw2, cb2, ew1, win, an, bn, out);
  }
}

// Round 11
// 610.440 us; speedup vs baseline: 1.0435x; 1.0435x over previous
//
#include <hip/hip_runtime.h>

#define WROW 52   // 13 time slices * 4 feats per node
#define TG 8      // targets per k_edge block (1024 blocks)

typedef _Float16 half_t;
typedef _Float16 half8 __attribute__((ext_vector_type(8)));
typedef float f32x4 __attribute__((ext_vector_type(4)));

#define SC 0.0009765625f   // 2^-10 activation pre-scale (exact power of 2)

// pack two f32 -> two f16 (RTZ) as a 32-bit word
__device__ __forceinline__ unsigned pkrtz(float a, float b) {
  auto v = __builtin_amdgcn_cvt_pkrtz(a, b);   // __fp16 x2
  return *(unsigned*)&v;
}

// ---------------- conv (2 layers) + edge-input projection -------------------
// LANES threads per node. cp: per-node scratch 160 floats.
// an/bn are stored PRE-SCALED by SC.
template<int LANES>
__device__ __forceinline__ void conv_proj(
    int lane, int gid, float* cp,
    const float* __restrict__ cw1, const float* __restrict__ cb1,
    const float* __restrict__ cw2, const float* __restrict__ cb2,
    const float* __restrict__ ew1,
    float* __restrict__ an, float* __restrict__ bn)
{
  #pragma unroll
  for (int o = 0; o < 96 / LANES; ++o) {
    int idx = lane + o * LANES;
    int tt = idx >> 5, f = idx & 31;
    float a = cb1[f];
    #pragma unroll
    for (int kt = 0; kt < 3; ++kt)
      #pragma unroll
      for (int d = 0; d < 4; ++d)
        a = fmaf(cp[(tt + kt) * 4 + d], cw1[(kt * 4 + d) * 32 + f], a);
    cp[32 + idx] = fmaxf(a, 0.f);
  }
  __syncthreads();
  #pragma unroll
  for (int o = 0; o < 32 / LANES; ++o) {
    int f = lane + o * LANES;
    float a = cb2[f];
    #pragma unroll
    for (int kt = 0; kt < 3; ++kt)
      for (int f1 = 0; f1 < 32; ++f1)
        a = fmaf(cp[32 + kt * 32 + f1], cw2[(kt * 32 + f1) * 32 + f], a);
    cp[128 + f] = fmaxf(a, 0.f);
  }
  __syncthreads();
  #pragma unroll
  for (int o = 0; o < 128 / LANES; ++o) {
    int j = lane + o * LANES;
    float a = 0.f, bb = 0.f;
    for (int f = 0; f < 32; ++f) {
      float h = cp[128 + f];
      a  = fmaf(h, ew1[f * 128 + j], a);
      bb = fmaf(h, ew1[(32 + f) * 128 + j], bb);
    }
    an[gid * 128 + j] = a * SC;
    bn[gid * 128 + j] = bb * SC;
  }
}

// ---------------- k_init: transpose + step-0 conv/proj ---------------------
__global__ __launch_bounds__(256) void k_init(
    const float* __restrict__ ts,
    const float* __restrict__ cw1, const float* __restrict__ cb1,
    const float* __restrict__ cw2, const float* __restrict__ cb2,
    const float* __restrict__ ew1,
    float* __restrict__ win, float* __restrict__ an, float* __restrict__ bn)
{
  __shared__ float cp[16 * 160];
  int blk = blockIdx.x;
  int b = blk >> 2, n0 = (blk & 3) << 4;
  int tid = threadIdx.x;
  int ln = tid >> 4, lane = tid & 15;
  int n = n0 + ln;
  int gid = b * 64 + n;
  float* mycp = cp + ln * 160;
  for (int idx = lane; idx < 20; idx += 16) {
    int tt = idx >> 2, d = idx & 3;
    float v = ts[((b * 5 + tt) * 64 + n) * 4 + d];
    mycp[idx] = v;
    win[gid * WROW + idx] = v;
  }
  __syncthreads();
  conv_proj<16>(lane, gid, mycp, cw1, cb1, cw2, cb2, ew1, an, bn);
}

// ---------------- k_wsplit: 5 weight mats -> f16 hi/lo B-fragment layout ---
// mat 0: ew2, 1: nw1, 2: nw2, 3: dw1[4:132], 4: dw2. dst = base (10x16384 halves)
__global__ __launch_bounds__(256) void k_wsplit(
    const float* __restrict__ ew2, const float* __restrict__ nw1,
    const float* __restrict__ nw2, const float* __restrict__ dw1,
    const float* __restrict__ dw2, half_t* __restrict__ dst)
{
  int mat = blockIdx.x >> 6;
  const float* src = (mat == 0) ? ew2 : (mat == 1) ? nw1 : (mat == 2) ? nw2
                   : (mat == 3) ? (dw1 + 512) : dw2;
  half_t* dh = dst + mat * 2 * 16384;
  half_t* dl = dh + 16384;
  int g = (blockIdx.x & 63) * 256 + threadIdx.x;   // k*128+col
  int k = g >> 7, col = g & 127;
  float x = src[g];
  _Float16 hi = (_Float16)x;
  float lo = x - (float)hi;
  int c = col >> 4, kb = k >> 5, kk = k & 31;
  int lane = ((kk >> 3) << 4) | (col & 15);
  int j = kk & 7;
  int idx = ((c * 4 + kb) * 64 + lane) * 8 + j;
  dh[idx] = hi;
  dl[idx] = (_Float16)lo;
}

// ---------------- k_edge_v8: v7 with correct launch bounds -----------------
// TG=8, 1024 blocks, 36 KB LDS, natural VGPR (~104 <= 128) -> 4 blocks/CU
// via LDS+VGPR limits (16 waves/CU), NO register cap, NO spills.
// C = 1024 * (Ah@Bh + Ah@Bl + Al@Bh), A = relu(anS + btS)  (pre-scaled 2^-10)
__global__ __launch_bounds__(256, 2) void k_edge_v8(
    const float* __restrict__ an, const float* __restrict__ bn,
    const float* __restrict__ eb1, const float* __restrict__ eb2,
    const half_t* __restrict__ Bh, const half_t* __restrict__ Bl,
    float* __restrict__ nm)
{
  __shared__ __align__(16) half_t sAh[8192];   // 16 KB
  __shared__ __align__(16) half_t sAl[8192];   // 16 KB
  __shared__ float s_bt[TG * 128];             // 4 KB
  int blk = blockIdx.x;
  int b = blk & 127, t0 = (blk >> 7) * TG;  // all 8 t-groups of b on one XCD
  int tid = threadIdx.x;
  int w = tid >> 6, lane = tid & 63;

  // ---- stage bt rows (+eb1*SC) into LDS (coalesced) ----
  #pragma unroll
  for (int i = 0; i < TG * 128 / 256; ++i) {
    int idx = tid + (i << 8);
    int tt = idx >> 7, j = idx & 127;
    s_bt[idx] = bn[((b << 6) + t0 + tt) * 128 + j] + eb1[j] * SC;
  }

  // ---- this thread's an slice in registers: rows it*16+(tid&15), kb8=tid>>4
  float au[4][8];
  {
    int kb8 = tid >> 4, sl = tid & 15;
    #pragma unroll
    for (int it = 0; it < 4; ++it) {
      const float* ap = an + (b << 13) + ((it * 16 + sl) << 7) + (kb8 << 3);
      float4 x0 = *(const float4*)ap;
      float4 x1 = *(const float4*)(ap + 4);
      au[it][0] = x0.x; au[it][1] = x0.y; au[it][2] = x0.z; au[it][3] = x0.w;
      au[it][4] = x1.x; au[it][5] = x1.y; au[it][6] = x1.z; au[it][7] = x1.w;
    }
  }

  // ---- B fragments in registers (tt-invariant): cols (w*2+cc)*16.. ----
  half8 rbh[2][4], rbl[2][4];
  #pragma unroll
  for (int cc = 0; cc < 2; ++cc)
    #pragma unroll
    for (int kb = 0; kb < 4; ++kb) {
      int c = w * 2 + cc;
      rbh[cc][kb] = *(const half8*)(Bh + ((c * 4 + kb) * 64 + lane) * 8);
      rbl[cc][kb] = *(const half8*)(Bl + ((c * 4 + kb) * 64 + lane) * 8);
    }

  float bias0 = eb2[(w * 2 + 0) * 16 + (lane & 15)];
  float bias1 = eb2[(w * 2 + 1) * 16 + (lane & 15)];
  int rowoff = (lane >> 4) * 4;

  __syncthreads();                 // s_bt ready

  for (int tt = 0; tt < TG; ++tt) {
    // ---- split(tt): relu(au + bt) -> f16 hi/lo fragments (write-linear) ----
    {
      const float* bp = s_bt + (tt << 7) + ((tid >> 4) << 3);
      float4 b0 = *(const float4*)bp;
      float4 b1 = *(const float4*)(bp + 4);
      float bs[8] = {b0.x, b0.y, b0.z, b0.w, b1.x, b1.y, b1.z, b1.w};
      #pragma unroll
      for (int it = 0; it < 4; ++it) {
        int u = tid + (it << 8);
        float h32[8], l32[8];
        #pragma unroll
        for (int i = 0; i < 8; ++i) {
          float x = fmaxf(au[it][i] + bs[i], 0.f);
          float h = __uint_as_float(__float_as_uint(x) & 0xffffe000u);
          h32[i] = h;
          l32[i] = x - h;
        }
        unsigned hw[4], lw[4];
        #pragma unroll
        for (int p = 0; p < 4; ++p) {
          hw[p] = pkrtz(h32[2 * p], h32[2 * p + 1]);
          lw[p] = pkrtz(l32[2 * p], l32[2 * p + 1]);
        }
        *(uint4*)(sAh + u * 8) = make_uint4(hw[0], hw[1], hw[2], hw[3]);
        *(uint4*)(sAl + u * 8) = make_uint4(lw[0], lw[1], lw[2], lw[3]);
      }
    }
    __syncthreads();               // fragments ready

    f32x4 acc[4][2];
    #pragma unroll
    for (int rr = 0; rr < 4; ++rr)
      #pragma unroll
      for (int cc = 0; cc < 2; ++cc)
        acc[rr][cc] = (f32x4){0.f, 0.f, 0.f, 0.f};

    #pragma unroll
    for (int kb = 0; kb < 4; ++kb) {
      half8 ah[4], al[4];
      #pragma unroll
      for (int rr = 0; rr < 4; ++rr) {
        ah[rr] = *(const half8*)(sAh + ((rr * 4 + kb) * 64 + lane) * 8);
        al[rr] = *(const half8*)(sAl + ((rr * 4 + kb) * 64 + lane) * 8);
      }
      #pragma unroll
      for (int cc = 0; cc < 2; ++cc)
        #pragma unroll
        for (int rr = 0; rr < 4; ++rr) {
          acc[rr][cc] = __builtin_amdgcn_mfma_f32_16x16x32_f16(ah[rr], rbh[cc][kb], acc[rr][cc], 0, 0, 0);
          acc[rr][cc] = __builtin_amdgcn_mfma_f32_16x16x32_f16(ah[rr], rbl[cc][kb], acc[rr][cc], 0, 0, 0);
          acc[rr][cc] = __builtin_amdgcn_mfma_f32_16x16x32_f16(al[rr], rbh[cc][kb], acc[rr][cc], 0, 0, 0);
        }
    }

    // epilogue: bias+relu, mask s==t, in-wave row reduction, coalesced store
    int t = t0 + tt;
    float csum0 = 0.f, csum1 = 0.f;
    #pragma unroll
    for (int rr = 0; rr < 4; ++rr) {
      int sbase = rr * 16 + rowoff;
      #pragma unroll
      for (int q = 0; q < 4; ++q) {
        int s = sbase + q;
        float y0 = acc[rr][0][q] * 1024.f + bias0;
        float y1 = acc[rr][1][q] * 1024.f + bias1;
        if (s != t) {
          csum0 += fmaxf(y0, 0.f);
          csum1 += fmaxf(y1, 0.f);
        }
      }
    }
    csum0 += __shfl_xor(csum0, 16, 64);
    csum0 += __shfl_xor(csum0, 32, 64);
    csum1 += __shfl_xor(csum1, 16, 64);
    csum1 += __shfl_xor(csum1, 32, 64);
    if (lane < 32)
      nm[((b << 6) + t) * 128 + w * 32 + lane] = (lane < 16) ? csum0 : csum1;
    __syncthreads();               // all reads of sA done before next split
  }
}

// ---------------- k_nd_mfma: node MLP + decoder via MFMA + head + conv -----
// 16 nodes/block, 512 blocks. 4 layers of [16x128]@[128x128] on matrix pipe.
__global__ __launch_bounds__(256) void k_nd_mfma(
    int step,
    const float* __restrict__ nm,
    const half_t* __restrict__ wsp,   // split weights base (Bh); mats 1..4 used
    const float* __restrict__ nb1, const float* __restrict__ nb2,
    const float* __restrict__ dw1, const float* __restrict__ db1,
    const float* __restrict__ db2,
    const float* __restrict__ ow,  const float* __restrict__ ob,
    const float* __restrict__ cw1, const float* __restrict__ cb1,
    const float* __restrict__ cw2, const float* __restrict__ cb2,
    const float* __restrict__ ew1,
    float* __restrict__ win, float* __restrict__ an, float* __restrict__ bn,
    float* __restrict__ out)
{
  __shared__ __align__(16) float Xraw[16][132];
  __shared__ __align__(16) half_t sAh[2048];
  __shared__ __align__(16) half_t sAl[2048];
  __shared__ float sP[16][4];
  __shared__ float s_dw1a[4 * 128];
  __shared__ float s_nxt[16][4];
  __shared__ float cp[16 * 160];

  int blk = blockIdx.x;
  int b = blk >> 2, n0 = (blk & 3) << 4;
  int tid = threadIdx.x;
  int w = tid >> 6, lane = tid & 63;

  // stage X = nm rows (coalesced float4), P, dw1 first 4 rows
  #pragma unroll
  for (int i = 0; i < 2; ++i) {
    int idx = tid + (i << 8);              // 512 float4s
    int row = idx >> 5, jf = idx & 31;
    *(float4*)&Xraw[row][jf << 2] =
        *(const float4*)(nm + ((b * 64 + n0 + row) << 7) + (jf << 2));
  }
  if (tid < 64) {
    int ln = tid >> 2, d = tid & 3;
    sP[ln][d] = win[(b * 64 + n0 + ln) * WROW + (step + 4) * 4 + d];
  }
  for (int idx = tid; idx < 512; idx += 256) s_dw1a[idx] = dw1[idx];
  __syncthreads();

  // split Xraw (scaled by SC) -> A-fragments, write-linear
  auto splitX = [&]() {
    int kb = tid >> 6, l = tid & 63;
    int row = l & 15, k0 = (kb << 5) + ((l >> 4) << 3);
    float h32[8], l32[8];
    #pragma unroll
    for (int i = 0; i < 8; ++i) {
      float x = Xraw[row][k0 + i] * SC;
      float h = __uint_as_float(__float_as_uint(x) & 0xffffe000u);
      h32[i] = h;
      l32[i] = x - h;
    }
    unsigned hw[4], lw[4];
    #pragma unroll
    for (int p = 0; p < 4; ++p) {
      hw[p] = pkrtz(h32[2 * p], h32[2 * p + 1]);
      lw[p] = pkrtz(l32[2 * p], l32[2 * p + 1]);
    }
    *(uint4*)(sAh + tid * 8) = make_uint4(hw[0], hw[1], hw[2], hw[3]);
    *(uint4*)(sAl + tid * 8) = make_uint4(lw[0], lw[1], lw[2], lw[3]);
  };

  // one dense layer: Xraw <- relu(Xraw @ W + bias [+ P@dw1a]), via MFMA
  auto layerM = [&](const half_t* Wh, const half_t* Wl,
                    const float* bias, bool withP) {
    splitX();
    __syncthreads();
    #pragma unroll
    for (int cc = 0; cc < 2; ++cc) {
      int c = w * 2 + cc;
      int col = c * 16 + (lane & 15);
      int row0 = (lane >> 4) * 4;
      float bj = bias[col];
      f32x4 acc;
      #pragma unroll
      for (int q = 0; q < 4; ++q) {
        float v = bj;
        if (withP) {
          #pragma unroll
          for (int d = 0; d < 4; ++d)
            v = fmaf(sP[row0 + q][d], s_dw1a[d * 128 + col], v);
        }
        acc[q] = v * SC;
      }
      #pragma unroll
      for (int kb = 0; kb < 4; ++kb) {
        half8 ah = *(const half8*)(sAh + ((kb << 6) + lane) * 8);
        half8 al = *(const half8*)(sAl + ((kb << 6) + lane) * 8);
        half8 bh = *(const half8*)(Wh + ((c * 4 + kb) * 64 + lane) * 8);
        half8 bl = *(const half8*)(Wl + ((c * 4 + kb) * 64 + lane) * 8);
        acc = __builtin_amdgcn_mfma_f32_16x16x32_f16(ah, bh, acc, 0, 0, 0);
        acc = __builtin_amdgcn_mfma_f32_16x16x32_f16(ah, bl, acc, 0, 0, 0);
        acc = __builtin_amdgcn_mfma_f32_16x16x32_f16(al, bh, acc, 0, 0, 0);
      }
      #pragma unroll
      for (int q = 0; q < 4; ++q)
        Xraw[row0 + q][col] = fmaxf(acc[q] * 1024.f, 0.f);
    }
    __syncthreads();
  };

  const half_t* nh1 = wsp + 2 * 16384;  const half_t* nl1 = nh1 + 16384;
  const half_t* nh2 = wsp + 4 * 16384;  const half_t* nl2 = nh2 + 16384;
  const half_t* dh1 = wsp + 6 * 16384;  const half_t* dl1 = dh1 + 16384;
  const half_t* dh2 = wsp + 8 * 16384;  const half_t* dl2 = dh2 + 16384;

  layerM(nh1, nl1, nb1, false);   // node mlp 1
  layerM(nh2, nl2, nb2, false);   // node mlp 2
  layerM(dh1, dl1, db1, true);    // dec 1 (P part via dw1 rows 0..3)
  layerM(dh2, dl2, db2, false);   // dec 2

  // output head: nxt = X @ ow + ob + prev  (k split 4-ways + shfl reduce)
  {
    int ln = tid >> 4, d = (tid >> 2) & 3, kq = tid & 3;
    float cs = 0.f;
    #pragma unroll
    for (int i = 0; i < 32; ++i) {
      int k = (kq << 5) + i;
      cs = fmaf(Xraw[ln][k], ow[k * 4 + d], cs);
    }
    cs += __shfl_xor(cs, 1, 64);
    cs += __shfl_xor(cs, 2, 64);
    if ((tid & 3) == 0) {
      float a = cs + ob[d] + sP[ln][d];
      int n = n0 + ln, gid = b * 64 + n;
      win[gid * WROW + (step + 5) * 4 + d] = a;
      out[((b * 8 + step) * 64 + n) * 4 + d] = a;
      s_nxt[ln][d] = a;
    }
  }
  __syncthreads();

  if (step < 7) {
    int ln = tid >> 4, lane2 = tid & 15;
    int gid = b * 64 + n0 + ln;
    float* mycp = cp + ln * 160;
    mycp[lane2] = win[gid * WROW + (step + 1) * 4 + lane2];
    if (lane2 < 4) mycp[16 + lane2] = s_nxt[ln][lane2];
    __syncthreads();
    conv_proj<16>(lane2, gid, mycp, cw1, cb1, cw2, cb2, ew1, an, bn);
  }
}

extern "C" void kernel_launch(void* const* d_in, const int* in_sizes, int n_in,
                              void* d_out, int out_size, void* d_ws, size_t ws_size,
                              hipStream_t stream) {
  (void)in_sizes; (void)n_in; (void)out_size; (void)ws_size;
  const float* ts  = (const float*)d_in[0];
  const float* cw1 = (const float*)d_in[1];
  const float* cb1 = (const float*)d_in[2];
  const float* cw2 = (const float*)d_in[3];
  const float* cb2 = (const float*)d_in[4];
  const float* ew1 = (const float*)d_in[5];
  const float* eb1 = (const float*)d_in[6];
  const float* ew2 = (const float*)d_in[7];
  const float* eb2 = (const float*)d_in[8];
  const float* nw1 = (const float*)d_in[9];
  const float* nb1 = (const float*)d_in[10];
  const float* nw2 = (const float*)d_in[11];
  const float* nb2 = (const float*)d_in[12];
  const float* dw1 = (const float*)d_in[13];
  const float* db1 = (const float*)d_in[14];
  const float* dw2 = (const float*)d_in[15];
  const float* db2 = (const float*)d_in[16];
  const float* ow  = (const float*)d_in[17];
  const float* ob  = (const float*)d_in[18];
  float* out = (float*)d_out;
  float* ws  = (float*)d_ws;
  float* win = ws;                        // 425984 floats
  float* an  = win + 425984;              // 1048576
  float* bn  = an + 1048576;              // 1048576
  float* nmb = bn + 1048576;              // 1048576
  half_t* wsp = (half_t*)(nmb + 1048576); // 10 x 16384 halves (Bh,Bl,Nh1,...)
  half_t* Bh = wsp;
  half_t* Bl = Bh + 16384;

  hipLaunchKernelGGL(k_wsplit, dim3(320), dim3(256), 0, stream,
                     ew2, nw1, nw2, dw1, dw2, wsp);
  hipLaunchKernelGGL(k_init, dim3(512), dim3(256), 0, stream,
                     ts, cw1, cb1, cw2, cb2, ew1, win, an, bn);
  for (int k = 0; k < 8; ++k) {
    hipLaunchKernelGGL(k_edge_v8, dim3(1024), dim3(256), 0, stream,
                       an, bn, eb1, eb2, Bh, Bl, nmb);
    hipLaunchKernelGGL(k_nd_mfma, dim3(512), dim3(256), 0, stream,
                       k, nmb, wsp, nb1, nb2, dw1, db1, db2,
                       ow, ob, cw1, cb1, cw2, cb2, ew1, win, an, bn, out);
  }
}

// Round 12
// 531.166 us; speedup vs baseline: 1.1993x; 1.1492x over previous
//
#include <hip/hip_runtime.h>

#define WROW 52   // 13 time slices * 4 feats per node
#define TG 16     // targets (= nodes) per k_step block

typedef _Float16 half_t;
typedef _Float16 half8 __attribute__((ext_vector_type(8)));
typedef float f32x4 __attribute__((ext_vector_type(4)));

#define SC 0.0009765625f   // 2^-10 activation pre-scale (exact power of 2)

__device__ __forceinline__ unsigned pkrtz(float a, float b) {
  auto v = __builtin_amdgcn_cvt_pkrtz(a, b);   // __fp16 x2
  return *(unsigned*)&v;
}

// ---------------- conv (2 layers) + edge-input projection -------------------
// LANES threads per node. cp: per-node scratch 160 floats.
// an/bn are stored PRE-SCALED by SC.
template<int LANES>
__device__ __forceinline__ void conv_proj(
    int lane, int gid, float* cp,
    const float* __restrict__ cw1, const float* __restrict__ cb1,
    const float* __restrict__ cw2, const float* __restrict__ cb2,
    const float* __restrict__ ew1,
    float* __restrict__ an, float* __restrict__ bn)
{
  #pragma unroll
  for (int o = 0; o < 96 / LANES; ++o) {
    int idx = lane + o * LANES;
    int tt = idx >> 5, f = idx & 31;
    float a = cb1[f];
    #pragma unroll
    for (int kt = 0; kt < 3; ++kt)
      #pragma unroll
      for (int d = 0; d < 4; ++d)
        a = fmaf(cp[(tt + kt) * 4 + d], cw1[(kt * 4 + d) * 32 + f], a);
    cp[32 + idx] = fmaxf(a, 0.f);
  }
  __syncthreads();
  #pragma unroll
  for (int o = 0; o < 32 / LANES; ++o) {
    int f = lane + o * LANES;
    float a = cb2[f];
    #pragma unroll
    for (int kt = 0; kt < 3; ++kt)
      for (int f1 = 0; f1 < 32; ++f1)
        a = fmaf(cp[32 + kt * 32 + f1], cw2[(kt * 32 + f1) * 32 + f], a);
    cp[128 + f] = fmaxf(a, 0.f);
  }
  __syncthreads();
  #pragma unroll
  for (int o = 0; o < 128 / LANES; ++o) {
    int j = lane + o * LANES;
    float a = 0.f, bb = 0.f;
    for (int f = 0; f < 32; ++f) {
      float h = cp[128 + f];
      a  = fmaf(h, ew1[f * 128 + j], a);
      bb = fmaf(h, ew1[(32 + f) * 128 + j], bb);
    }
    an[gid * 128 + j] = a * SC;
    bn[gid * 128 + j] = bb * SC;
  }
}

// ---------------- k_init: transpose + step-0 conv/proj ---------------------
__global__ __launch_bounds__(256) void k_init(
    const float* __restrict__ ts,
    const float* __restrict__ cw1, const float* __restrict__ cb1,
    const float* __restrict__ cw2, const float* __restrict__ cb2,
    const float* __restrict__ ew1,
    float* __restrict__ win, float* __restrict__ an, float* __restrict__ bn)
{
  __shared__ float cp[16 * 160];
  int blk = blockIdx.x;
  int b = blk >> 2, n0 = (blk & 3) << 4;
  int tid = threadIdx.x;
  int ln = tid >> 4, lane = tid & 15;
  int n = n0 + ln;
  int gid = b * 64 + n;
  float* mycp = cp + ln * 160;
  for (int idx = lane; idx < 20; idx += 16) {
    int tt = idx >> 2, d = idx & 3;
    float v = ts[((b * 5 + tt) * 64 + n) * 4 + d];
    mycp[idx] = v;
    win[gid * WROW + idx] = v;
  }
  __syncthreads();
  conv_proj<16>(lane, gid, mycp, cw1, cb1, cw2, cb2, ew1, an, bn);
}

// ---------------- k_wsplit: 5 weight mats -> f16 hi/lo B-fragment layout ---
// mat 0: ew2, 1: nw1, 2: nw2, 3: dw1[4:132], 4: dw2. dst = base (10x16384 halves)
__global__ __launch_bounds__(256) void k_wsplit(
    const float* __restrict__ ew2, const float* __restrict__ nw1,
    const float* __restrict__ nw2, const float* __restrict__ dw1,
    const float* __restrict__ dw2, half_t* __restrict__ dst)
{
  int mat = blockIdx.x >> 6;
  const float* src = (mat == 0) ? ew2 : (mat == 1) ? nw1 : (mat == 2) ? nw2
                   : (mat == 3) ? (dw1 + 512) : dw2;
  half_t* dh = dst + mat * 2 * 16384;
  half_t* dl = dh + 16384;
  int g = (blockIdx.x & 63) * 256 + threadIdx.x;   // k*128+col
  int k = g >> 7, col = g & 127;
  float x = src[g];
  _Float16 hi = (_Float16)x;
  float lo = x - (float)hi;
  int c = col >> 4, kb = k >> 5, kk = k & 31;
  int lane = ((kk >> 3) << 4) | (col & 15);
  int j = kk & 7;
  int idx = ((c * 4 + kb) * 64 + lane) * 8 + j;
  dh[idx] = hi;
  dl[idx] = (_Float16)lo;
}

// ---------------- k_step: FUSED edge GEMM + node/dec MLPs + head + conv ----
// Block = (b, group of 16 targets == 16 nodes). Edge phase writes node_msg
// rows straight into LDS X; nd phase consumes them. an/bn are ping-ponged
// across steps (anR/bnR read, anW/bnW written) to avoid same-launch WAR.
__global__ __launch_bounds__(256, 2) void k_step(
    int step,
    const float* __restrict__ anR, const float* __restrict__ bnR,
    float* __restrict__ anW, float* __restrict__ bnW,
    const float* __restrict__ eb1, const float* __restrict__ eb2,
    const half_t* __restrict__ wsp,
    const float* __restrict__ nb1, const float* __restrict__ nb2,
    const float* __restrict__ dw1, const float* __restrict__ db1,
    const float* __restrict__ db2,
    const float* __restrict__ ow,  const float* __restrict__ ob,
    const float* __restrict__ cw1, const float* __restrict__ cb1,
    const float* __restrict__ cw2, const float* __restrict__ cb2,
    const float* __restrict__ ew1,
    float* __restrict__ win, float* __restrict__ out)
{
  // 40 KB aliased region + 8.25 KB X
  __shared__ __align__(16) unsigned char smem[40960];
  __shared__ __align__(16) float X[16][132];
  // edge-phase views
  half_t* sAh = (half_t*)smem;                     // 16 KB
  half_t* sAl = (half_t*)(smem + 16384);           // 16 KB
  float*  s_bt = (float*)(smem + 32768);           // 8 KB
  // nd-phase views (alias sAh/sAl region; edge phase is over when used)
  half_t* nAh = (half_t*)smem;                     // 4 KB
  half_t* nAl = (half_t*)(smem + 4096);            // 4 KB
  float*  cp     = (float*)(smem + 16640);         // 10 KB
  float*  s_dw1a = (float*)(smem + 26880);         // 2 KB
  float (*sP)[4]   = (float(*)[4])(smem + 28928);  // 256 B
  float (*s_nxt)[4] = (float(*)[4])(smem + 29184); // 256 B

  int blk = blockIdx.x;
  int b = blk & 127, t0 = (blk >> 7) * TG;
  int tid = threadIdx.x;
  int w = tid >> 6, lane = tid & 63;

  const half_t* Bh = wsp;
  const half_t* Bl = wsp + 16384;

  // =================== EDGE PHASE (v6 numerics, single buffer) ===========
  #pragma unroll
  for (int i = 0; i < TG * 128 / 256; ++i) {
    int idx = tid + (i << 8);
    int tt = idx >> 7, j = idx & 127;
    s_bt[idx] = bnR[((b << 6) + t0 + tt) * 128 + j] + eb1[j] * SC;
  }

  float au[4][8];
  {
    int kb8 = tid >> 4, sl = tid & 15;
    #pragma unroll
    for (int it = 0; it < 4; ++it) {
      const float* ap = anR + (b << 13) + ((it * 16 + sl) << 7) + (kb8 << 3);
      float4 x0 = *(const float4*)ap;
      float4 x1 = *(const float4*)(ap + 4);
      au[it][0] = x0.x; au[it][1] = x0.y; au[it][2] = x0.z; au[it][3] = x0.w;
      au[it][4] = x1.x; au[it][5] = x1.y; au[it][6] = x1.z; au[it][7] = x1.w;
    }
  }

  half8 rbh[2][4], rbl[2][4];
  #pragma unroll
  for (int cc = 0; cc < 2; ++cc)
    #pragma unroll
    for (int kb = 0; kb < 4; ++kb) {
      int c = w * 2 + cc;
      rbh[cc][kb] = *(const half8*)(Bh + ((c * 4 + kb) * 64 + lane) * 8);
      rbl[cc][kb] = *(const half8*)(Bl + ((c * 4 + kb) * 64 + lane) * 8);
    }

  float bias0 = eb2[(w * 2 + 0) * 16 + (lane & 15)];
  float bias1 = eb2[(w * 2 + 1) * 16 + (lane & 15)];
  int rowoff = (lane >> 4) * 4;

  __syncthreads();                 // s_bt ready

  for (int tt = 0; tt < TG; ++tt) {
    {  // split(tt): relu(au + bt) -> f16 hi/lo fragments (write-linear)
      const float* bp = s_bt + (tt << 7) + ((tid >> 4) << 3);
      float4 b0 = *(const float4*)bp;
      float4 b1 = *(const float4*)(bp + 4);
      float bs[8] = {b0.x, b0.y, b0.z, b0.w, b1.x, b1.y, b1.z, b1.w};
      #pragma unroll
      for (int it = 0; it < 4; ++it) {
        int u = tid + (it << 8);
        float h32[8], l32[8];
        #pragma unroll
        for (int i = 0; i < 8; ++i) {
          float x = fmaxf(au[it][i] + bs[i], 0.f);
          float h = __uint_as_float(__float_as_uint(x) & 0xffffe000u);
          h32[i] = h;
          l32[i] = x - h;
        }
        unsigned hw[4], lw[4];
        #pragma unroll
        for (int p = 0; p < 4; ++p) {
          hw[p] = pkrtz(h32[2 * p], h32[2 * p + 1]);
          lw[p] = pkrtz(l32[2 * p], l32[2 * p + 1]);
        }
        *(uint4*)(sAh + u * 8) = make_uint4(hw[0], hw[1], hw[2], hw[3]);
        *(uint4*)(sAl + u * 8) = make_uint4(lw[0], lw[1], lw[2], lw[3]);
      }
    }
    __syncthreads();               // fragments ready

    f32x4 acc[4][2];
    #pragma unroll
    for (int rr = 0; rr < 4; ++rr)
      #pragma unroll
      for (int cc = 0; cc < 2; ++cc)
        acc[rr][cc] = (f32x4){0.f, 0.f, 0.f, 0.f};

    #pragma unroll
    for (int kb = 0; kb < 4; ++kb) {
      half8 ah[4], al[4];
      #pragma unroll
      for (int rr = 0; rr < 4; ++rr) {
        ah[rr] = *(const half8*)(sAh + ((rr * 4 + kb) * 64 + lane) * 8);
        al[rr] = *(const half8*)(sAl + ((rr * 4 + kb) * 64 + lane) * 8);
      }
      #pragma unroll
      for (int cc = 0; cc < 2; ++cc)
        #pragma unroll
        for (int rr = 0; rr < 4; ++rr) {
          acc[rr][cc] = __builtin_amdgcn_mfma_f32_16x16x32_f16(ah[rr], rbh[cc][kb], acc[rr][cc], 0, 0, 0);
          acc[rr][cc] = __builtin_amdgcn_mfma_f32_16x16x32_f16(ah[rr], rbl[cc][kb], acc[rr][cc], 0, 0, 0);
          acc[rr][cc] = __builtin_amdgcn_mfma_f32_16x16x32_f16(al[rr], rbh[cc][kb], acc[rr][cc], 0, 0, 0);
        }
    }

    int t = t0 + tt;
    float csum0 = 0.f, csum1 = 0.f;
    #pragma unroll
    for (int rr = 0; rr < 4; ++rr) {
      int sbase = rr * 16 + rowoff;
      #pragma unroll
      for (int q = 0; q < 4; ++q) {
        int s = sbase + q;
        float y0 = acc[rr][0][q] * 1024.f + bias0;
        float y1 = acc[rr][1][q] * 1024.f + bias1;
        if (s != t) {
          csum0 += fmaxf(y0, 0.f);
          csum1 += fmaxf(y1, 0.f);
        }
      }
    }
    csum0 += __shfl_xor(csum0, 16, 64);
    csum0 += __shfl_xor(csum0, 32, 64);
    csum1 += __shfl_xor(csum1, 16, 64);
    csum1 += __shfl_xor(csum1, 32, 64);
    if (lane < 32)
      X[tt][w * 32 + lane] = (lane < 16) ? csum0 : csum1;  // node_msg -> LDS
    __syncthreads();               // sA reads done; X row complete
  }

  // =================== ND PHASE (k_nd_mfma verbatim, X in LDS) ===========
  if (tid < 64) {
    int ln = tid >> 2, d = tid & 3;
    sP[ln][d] = win[(b * 64 + t0 + ln) * WROW + (step + 4) * 4 + d];
  }
  for (int idx = tid; idx < 512; idx += 256) s_dw1a[idx] = dw1[idx];
  __syncthreads();

  auto splitX = [&]() {
    int kb = tid >> 6, l = tid & 63;
    int row = l & 15, k0 = (kb << 5) + ((l >> 4) << 3);
    float h32[8], l32[8];
    #pragma unroll
    for (int i = 0; i < 8; ++i) {
      float x = X[row][k0 + i] * SC;
      float h = __uint_as_float(__float_as_uint(x) & 0xffffe000u);
      h32[i] = h;
      l32[i] = x - h;
    }
    unsigned hw[4], lw[4];
    #pragma unroll
    for (int p = 0; p < 4; ++p) {
      hw[p] = pkrtz(h32[2 * p], h32[2 * p + 1]);
      lw[p] = pkrtz(l32[2 * p], l32[2 * p + 1]);
    }
    *(uint4*)(nAh + tid * 8) = make_uint4(hw[0], hw[1], hw[2], hw[3]);
    *(uint4*)(nAl + tid * 8) = make_uint4(lw[0], lw[1], lw[2], lw[3]);
  };

  auto layerM = [&](const half_t* Wh, const half_t* Wl,
                    const float* bias, bool withP) {
    splitX();
    __syncthreads();
    #pragma unroll
    for (int cc = 0; cc < 2; ++cc) {
      int c = w * 2 + cc;
      int col = c * 16 + (lane & 15);
      int row0 = (lane >> 4) * 4;
      float bj = bias[col];
      f32x4 acc;
      #pragma unroll
      for (int q = 0; q < 4; ++q) {
        float v = bj;
        if (withP) {
          #pragma unroll
          for (int d = 0; d < 4; ++d)
            v = fmaf(sP[row0 + q][d], s_dw1a[d * 128 + col], v);
        }
        acc[q] = v * SC;
      }
      #pragma unroll
      for (int kb = 0; kb < 4; ++kb) {
        half8 ah = *(const half8*)(nAh + ((kb << 6) + lane) * 8);
        half8 al = *(const half8*)(nAl + ((kb << 6) + lane) * 8);
        half8 bh = *(const half8*)(Wh + ((c * 4 + kb) * 64 + lane) * 8);
        half8 bl = *(const half8*)(Wl + ((c * 4 + kb) * 64 + lane) * 8);
        acc = __builtin_amdgcn_mfma_f32_16x16x32_f16(ah, bh, acc, 0, 0, 0);
        acc = __builtin_amdgcn_mfma_f32_16x16x32_f16(ah, bl, acc, 0, 0, 0);
        acc = __builtin_amdgcn_mfma_f32_16x16x32_f16(al, bh, acc, 0, 0, 0);
      }
      #pragma unroll
      for (int q = 0; q < 4; ++q)
        X[row0 + q][col] = fmaxf(acc[q] * 1024.f, 0.f);
    }
    __syncthreads();
  };

  const half_t* nh1 = wsp + 2 * 16384;  const half_t* nl1 = nh1 + 16384;
  const half_t* nh2 = wsp + 4 * 16384;  const half_t* nl2 = nh2 + 16384;
  const half_t* dh1 = wsp + 6 * 16384;  const half_t* dl1 = dh1 + 16384;
  const half_t* dh2 = wsp + 8 * 16384;  const half_t* dl2 = dh2 + 16384;

  layerM(nh1, nl1, nb1, false);   // node mlp 1
  layerM(nh2, nl2, nb2, false);   // node mlp 2
  layerM(dh1, dl1, db1, true);    // dec 1 (P part via dw1 rows 0..3)
  layerM(dh2, dl2, db2, false);   // dec 2

  // output head: nxt = X @ ow + ob + prev
  {
    int ln = tid >> 4, d = (tid >> 2) & 3, kq = tid & 3;
    float cs = 0.f;
    #pragma unroll
    for (int i = 0; i < 32; ++i) {
      int k = (kq << 5) + i;
      cs = fmaf(X[ln][k], ow[k * 4 + d], cs);
    }
    cs += __shfl_xor(cs, 1, 64);
    cs += __shfl_xor(cs, 2, 64);
    if ((tid & 3) == 0) {
      float a = cs + ob[d] + sP[ln][d];
      int n = t0 + ln, gid = b * 64 + n;
      win[gid * WROW + (step + 5) * 4 + d] = a;
      out[((b * 8 + step) * 64 + n) * 4 + d] = a;
      s_nxt[ln][d] = a;
    }
  }
  __syncthreads();

  if (step < 7) {
    int ln = tid >> 4, lane2 = tid & 15;
    int gid = b * 64 + t0 + ln;
    float* mycp = cp + ln * 160;
    mycp[lane2] = win[gid * WROW + (step + 1) * 4 + lane2];
    if (lane2 < 4) mycp[16 + lane2] = s_nxt[ln][lane2];
    __syncthreads();
    conv_proj<16>(lane2, gid, mycp, cw1, cb1, cw2, cb2, ew1, anW, bnW);
  }
}

extern "C" void kernel_launch(void* const* d_in, const int* in_sizes, int n_in,
                              void* d_out, int out_size, void* d_ws, size_t ws_size,
                              hipStream_t stream) {
  (void)in_sizes; (void)n_in; (void)out_size; (void)ws_size;
  const float* ts  = (const float*)d_in[0];
  const float* cw1 = (const float*)d_in[1];
  const float* cb1 = (const float*)d_in[2];
  const float* cw2 = (const float*)d_in[3];
  const float* cb2 = (const float*)d_in[4];
  const float* ew1 = (const float*)d_in[5];
  const float* eb1 = (const float*)d_in[6];
  const float* ew2 = (const float*)d_in[7];
  const float* eb2 = (const float*)d_in[8];
  const float* nw1 = (const float*)d_in[9];
  const float* nb1 = (const float*)d_in[10];
  const float* nw2 = (const float*)d_in[11];
  const float* nb2 = (const float*)d_in[12];
  const float* dw1 = (const float*)d_in[13];
  const float* db1 = (const float*)d_in[14];
  const float* dw2 = (const float*)d_in[15];
  const float* db2 = (const float*)d_in[16];
  const float* ow  = (const float*)d_in[17];
  const float* ob  = (const float*)d_in[18];
  float* out = (float*)d_out;
  float* ws  = (float*)d_ws;
  float* win = ws;                        // 425984 floats
  float* an0 = win + 425984;              // 1048576
  float* bn0 = an0 + 1048576;             // 1048576
  float* an1 = bn0 + 1048576;             // 1048576
  float* bn1 = an1 + 1048576;             // 1048576
  half_t* wsp = (half_t*)(bn1 + 1048576); // 10 x 16384 halves

  hipLaunchKernelGGL(k_wsplit, dim3(320), dim3(256), 0, stream,
                     ew2, nw1, nw2, dw1, dw2, wsp);
  hipLaunchKernelGGL(k_init, dim3(512), dim3(256), 0, stream,
                     ts, cw1, cb1, cw2, cb2, ew1, win, an0, bn0);
  for (int k = 0; k < 8; ++k) {
    const float* anR = (k & 1) ? an1 : an0;
    const float* bnR = (k & 1) ? bn1 : bn0;
    float* anW = (k & 1) ? an0 : an1;
    float* bnW = (k & 1) ? bn0 : bn1;
    hipLaunchKernelGGL(k_step, dim3(512), dim3(256), 0, stream,
                       k, anR, bnR, anW, bnW, eb1, eb2, wsp,
                       nb1, nb2, dw1, db1, db2, ow, ob,
                       cw1, cb1, cw2, cb2, ew1, win, out);
  }
}

// Round 13
// 494.908 us; speedup vs baseline: 1.2872x; 1.0733x over previous
//
#include <hip/hip_runtime.h>

#define WROW 52   // 13 time slices * 4 feats per node
#define TG 16     // targets (= nodes) per k_step block

typedef _Float16 half_t;
typedef _Float16 half8 __attribute__((ext_vector_type(8)));
typedef float f32x4 __attribute__((ext_vector_type(4)));

#define SC 0.0009765625f   // 2^-10 activation pre-scale (exact power of 2)

__device__ __forceinline__ unsigned pkrtz(float a, float b) {
  auto v = __builtin_amdgcn_cvt_pkrtz(a, b);   // __fp16 x2
  return *(unsigned*)&v;
}

// ---------------- conv (2 layers) + edge-input projection -------------------
template<int LANES>
__device__ __forceinline__ void conv_proj(
    int lane, int gid, float* cp,
    const float* __restrict__ cw1, const float* __restrict__ cb1,
    const float* __restrict__ cw2, const float* __restrict__ cb2,
    const float* __restrict__ ew1,
    float* __restrict__ an, float* __restrict__ bn)
{
  #pragma unroll
  for (int o = 0; o < 96 / LANES; ++o) {
    int idx = lane + o * LANES;
    int tt = idx >> 5, f = idx & 31;
    float a = cb1[f];
    #pragma unroll
    for (int kt = 0; kt < 3; ++kt)
      #pragma unroll
      for (int d = 0; d < 4; ++d)
        a = fmaf(cp[(tt + kt) * 4 + d], cw1[(kt * 4 + d) * 32 + f], a);
    cp[32 + idx] = fmaxf(a, 0.f);
  }
  __syncthreads();
  #pragma unroll
  for (int o = 0; o < 32 / LANES; ++o) {
    int f = lane + o * LANES;
    float a = cb2[f];
    #pragma unroll
    for (int kt = 0; kt < 3; ++kt)
      for (int f1 = 0; f1 < 32; ++f1)
        a = fmaf(cp[32 + kt * 32 + f1], cw2[(kt * 32 + f1) * 32 + f], a);
    cp[128 + f] = fmaxf(a, 0.f);
  }
  __syncthreads();
  #pragma unroll
  for (int o = 0; o < 128 / LANES; ++o) {
    int j = lane + o * LANES;
    float a = 0.f, bb = 0.f;
    for (int f = 0; f < 32; ++f) {
      float h = cp[128 + f];
      a  = fmaf(h, ew1[f * 128 + j], a);
      bb = fmaf(h, ew1[(32 + f) * 128 + j], bb);
    }
    an[gid * 128 + j] = a * SC;
    bn[gid * 128 + j] = bb * SC;
  }
}

// ---------------- k_init: transpose + step-0 conv/proj ---------------------
__global__ __launch_bounds__(256) void k_init(
    const float* __restrict__ ts,
    const float* __restrict__ cw1, const float* __restrict__ cb1,
    const float* __restrict__ cw2, const float* __restrict__ cb2,
    const float* __restrict__ ew1,
    float* __restrict__ win, float* __restrict__ an, float* __restrict__ bn)
{
  __shared__ float cp[16 * 160];
  int blk = blockIdx.x;
  int b = blk >> 2, n0 = (blk & 3) << 4;
  int tid = threadIdx.x;
  int ln = tid >> 4, lane = tid & 15;
  int n = n0 + ln;
  int gid = b * 64 + n;
  float* mycp = cp + ln * 160;
  for (int idx = lane; idx < 20; idx += 16) {
    int tt = idx >> 2, d = idx & 3;
    float v = ts[((b * 5 + tt) * 64 + n) * 4 + d];
    mycp[idx] = v;
    win[gid * WROW + idx] = v;
  }
  __syncthreads();
  conv_proj<16>(lane, gid, mycp, cw1, cb1, cw2, cb2, ew1, an, bn);
}

// ---------------- k_wsplit: 5 weight mats -> f16 hi/lo B-fragment layout ---
__global__ __launch_bounds__(256) void k_wsplit(
    const float* __restrict__ ew2, const float* __restrict__ nw1,
    const float* __restrict__ nw2, const float* __restrict__ dw1,
    const float* __restrict__ dw2, half_t* __restrict__ dst)
{
  int mat = blockIdx.x >> 6;
  const float* src = (mat == 0) ? ew2 : (mat == 1) ? nw1 : (mat == 2) ? nw2
                   : (mat == 3) ? (dw1 + 512) : dw2;
  half_t* dh = dst + mat * 2 * 16384;
  half_t* dl = dh + 16384;
  int g = (blockIdx.x & 63) * 256 + threadIdx.x;   // k*128+col
  int k = g >> 7, col = g & 127;
  float x = src[g];
  _Float16 hi = (_Float16)x;
  float lo = x - (float)hi;
  int c = col >> 4, kb = k >> 5, kk = k & 31;
  int lane = ((kk >> 3) << 4) | (col & 15);
  int j = kk & 7;
  int idx = ((c * 4 + kb) * 64 + lane) * 8 + j;
  dh[idx] = hi;
  dl[idx] = (_Float16)lo;
}

// ---------------- k_step: FUSED edge GEMM + node/dec MLPs + head + conv ----
// Edge phase uses 2x2 wave ownership: wave (wr,wc) = rows wr*32, cols wc*64.
// A-fragment LDS reads halve (16/wave/tt); row-sum combined via s_part.
__global__ __launch_bounds__(256, 2) void k_step(
    int step,
    const float* __restrict__ anR, const float* __restrict__ bnR,
    float* __restrict__ anW, float* __restrict__ bnW,
    const float* __restrict__ eb1, const float* __restrict__ eb2,
    const half_t* __restrict__ wsp,
    const float* __restrict__ nb1, const float* __restrict__ nb2,
    const float* __restrict__ dw1, const float* __restrict__ db1,
    const float* __restrict__ db2,
    const float* __restrict__ ow,  const float* __restrict__ ob,
    const float* __restrict__ cw1, const float* __restrict__ cb1,
    const float* __restrict__ cw2, const float* __restrict__ cb2,
    const float* __restrict__ ew1,
    float* __restrict__ win, float* __restrict__ out)
{
  __shared__ __align__(16) unsigned char smem[40960];
  __shared__ __align__(16) float X[16][132];
  __shared__ float s_part[2][128];
  // edge-phase views
  half_t* sAh = (half_t*)smem;                     // 16 KB
  half_t* sAl = (half_t*)(smem + 16384);           // 16 KB
  float*  s_bt = (float*)(smem + 32768);           // 8 KB
  // nd-phase views (alias; edge phase over when used)
  half_t* nAh = (half_t*)smem;                     // 4 KB
  half_t* nAl = (half_t*)(smem + 4096);            // 4 KB
  float*  cp     = (float*)(smem + 16640);         // 10 KB
  float*  s_dw1a = (float*)(smem + 26880);         // 2 KB
  float (*sP)[4]   = (float(*)[4])(smem + 28928);  // 256 B
  float (*s_nxt)[4] = (float(*)[4])(smem + 29184); // 256 B

  int blk = blockIdx.x;
  int b = blk & 127, t0 = (blk >> 7) * TG;
  int tid = threadIdx.x;
  int w = tid >> 6, lane = tid & 63;
  int wr = w >> 1, wc = w & 1;

  const half_t* Bh = wsp;
  const half_t* Bl = wsp + 16384;

  // =================== EDGE PHASE ===================
  #pragma unroll
  for (int i = 0; i < TG * 128 / 256; ++i) {
    int idx = tid + (i << 8);
    int tt = idx >> 7, j = idx & 127;
    s_bt[idx] = bnR[((b << 6) + t0 + tt) * 128 + j] + eb1[j] * SC;
  }

  float au[4][8];
  {
    int kb8 = tid >> 4, sl = tid & 15;
    #pragma unroll
    for (int it = 0; it < 4; ++it) {
      const float* ap = anR + (b << 13) + ((it * 16 + sl) << 7) + (kb8 << 3);
      float4 x0 = *(const float4*)ap;
      float4 x1 = *(const float4*)(ap + 4);
      au[it][0] = x0.x; au[it][1] = x0.y; au[it][2] = x0.z; au[it][3] = x0.w;
      au[it][4] = x1.x; au[it][5] = x1.y; au[it][6] = x1.z; au[it][7] = x1.w;
    }
  }

  // B fragments: this wave's 4 col-tiles (cols wc*64 .. +63)
  half8 rbh[4][4], rbl[4][4];
  #pragma unroll
  for (int cc = 0; cc < 4; ++cc)
    #pragma unroll
    for (int kb = 0; kb < 4; ++kb) {
      int c = wc * 4 + cc;
      rbh[cc][kb] = *(const half8*)(Bh + ((c * 4 + kb) * 64 + lane) * 8);
      rbl[cc][kb] = *(const half8*)(Bl + ((c * 4 + kb) * 64 + lane) * 8);
    }

  float biasc[4];
  #pragma unroll
  for (int cc = 0; cc < 4; ++cc)
    biasc[cc] = eb2[(wc * 4 + cc) * 16 + (lane & 15)];
  int rowoff = (lane >> 4) * 4;

  __syncthreads();                 // s_bt ready

  for (int tt = 0; tt < TG; ++tt) {
    {  // split(tt): relu(au + bt) -> f16 hi/lo fragments (write-linear)
      const float* bp = s_bt + (tt << 7) + ((tid >> 4) << 3);
      float4 b0 = *(const float4*)bp;
      float4 b1 = *(const float4*)(bp + 4);
      float bs[8] = {b0.x, b0.y, b0.z, b0.w, b1.x, b1.y, b1.z, b1.w};
      #pragma unroll
      for (int it = 0; it < 4; ++it) {
        int u = tid + (it << 8);
        float h32[8], l32[8];
        #pragma unroll
        for (int i = 0; i < 8; ++i) {
          float x = fmaxf(au[it][i] + bs[i], 0.f);
          float h = __uint_as_float(__float_as_uint(x) & 0xffffe000u);
          h32[i] = h;
          l32[i] = x - h;
        }
        unsigned hw[4], lw[4];
        #pragma unroll
        for (int p = 0; p < 4; ++p) {
          hw[p] = pkrtz(h32[2 * p], h32[2 * p + 1]);
          lw[p] = pkrtz(l32[2 * p], l32[2 * p + 1]);
        }
        *(uint4*)(sAh + u * 8) = make_uint4(hw[0], hw[1], hw[2], hw[3]);
        *(uint4*)(sAl + u * 8) = make_uint4(lw[0], lw[1], lw[2], lw[3]);
      }
    }
    __syncthreads();               // fragments ready

    f32x4 acc[2][4];
    #pragma unroll
    for (int rr = 0; rr < 2; ++rr)
      #pragma unroll
      for (int cc = 0; cc < 4; ++cc)
        acc[rr][cc] = (f32x4){0.f, 0.f, 0.f, 0.f};

    #pragma unroll
    for (int kb = 0; kb < 4; ++kb) {
      half8 ah[2], al[2];
      #pragma unroll
      for (int rr = 0; rr < 2; ++rr) {
        int rt = wr * 2 + rr;
        ah[rr] = *(const half8*)(sAh + ((rt * 4 + kb) * 64 + lane) * 8);
        al[rr] = *(const half8*)(sAl + ((rt * 4 + kb) * 64 + lane) * 8);
      }
      #pragma unroll
      for (int cc = 0; cc < 4; ++cc)
        #pragma unroll
        for (int rr = 0; rr < 2; ++rr) {
          acc[rr][cc] = __builtin_amdgcn_mfma_f32_16x16x32_f16(ah[rr], rbh[cc][kb], acc[rr][cc], 0, 0, 0);
          acc[rr][cc] = __builtin_amdgcn_mfma_f32_16x16x32_f16(ah[rr], rbl[cc][kb], acc[rr][cc], 0, 0, 0);
          acc[rr][cc] = __builtin_amdgcn_mfma_f32_16x16x32_f16(al[rr], rbh[cc][kb], acc[rr][cc], 0, 0, 0);
        }
    }

    // epilogue: bias+relu, mask s==t, reduce this wave's 32 rows, combine
    int t = t0 + tt;
    float csum[4] = {0.f, 0.f, 0.f, 0.f};
    #pragma unroll
    for (int cc = 0; cc < 4; ++cc) {
      #pragma unroll
      for (int rr = 0; rr < 2; ++rr) {
        int sbase = (wr * 2 + rr) * 16 + rowoff;
        #pragma unroll
        for (int q = 0; q < 4; ++q) {
          int s = sbase + q;
          float y = acc[rr][cc][q] * 1024.f + biasc[cc];
          if (s != t) csum[cc] += fmaxf(y, 0.f);
        }
      }
    }
    #pragma unroll
    for (int cc = 0; cc < 4; ++cc) {
      csum[cc] += __shfl_xor(csum[cc], 16, 64);
      csum[cc] += __shfl_xor(csum[cc], 32, 64);
    }
    if (lane < 16) {
      #pragma unroll
      for (int cc = 0; cc < 4; ++cc)
        s_part[wr][(wc * 4 + cc) * 16 + lane] = csum[cc];
    }
    __syncthreads();               // sA reads done; s_part ready
    if (tid < 128)
      X[tt][tid] = s_part[0][tid] + s_part[1][tid];   // node_msg -> LDS
    // next split overwrites sA (safe: all reads done); s_part overwritten
    // only after the NEXT epilogue's barrier, X readers sync in nd phase.
  }
  __syncthreads();

  // =================== ND PHASE ===================
  if (tid < 64) {
    int ln = tid >> 2, d = tid & 3;
    sP[ln][d] = win[(b * 64 + t0 + ln) * WROW + (step + 4) * 4 + d];
  }
  for (int idx = tid; idx < 512; idx += 256) s_dw1a[idx] = dw1[idx];
  __syncthreads();

  auto splitX = [&]() {
    int kb = tid >> 6, l = tid & 63;
    int row = l & 15, k0 = (kb << 5) + ((l >> 4) << 3);
    float h32[8], l32[8];
    #pragma unroll
    for (int i = 0; i < 8; ++i) {
      float x = X[row][k0 + i] * SC;
      float h = __uint_as_float(__float_as_uint(x) & 0xffffe000u);
      h32[i] = h;
      l32[i] = x - h;
    }
    unsigned hw[4], lw[4];
    #pragma unroll
    for (int p = 0; p < 4; ++p) {
      hw[p] = pkrtz(h32[2 * p], h32[2 * p + 1]);
      lw[p] = pkrtz(l32[2 * p], l32[2 * p + 1]);
    }
    *(uint4*)(nAh + tid * 8) = make_uint4(hw[0], hw[1], hw[2], hw[3]);
    *(uint4*)(nAl + tid * 8) = make_uint4(lw[0], lw[1], lw[2], lw[3]);
  };

  auto layerM = [&](const half_t* Wh, const half_t* Wl,
                    const float* bias, bool withP) {
    splitX();
    __syncthreads();
    #pragma unroll
    for (int cc = 0; cc < 2; ++cc) {
      int c = w * 2 + cc;
      int col = c * 16 + (lane & 15);
      int row0 = (lane >> 4) * 4;
      float bj = bias[col];
      f32x4 acc;
      #pragma unroll
      for (int q = 0; q < 4; ++q) {
        float v = bj;
        if (withP) {
          #pragma unroll
          for (int d = 0; d < 4; ++d)
            v = fmaf(sP[row0 + q][d], s_dw1a[d * 128 + col], v);
        }
        acc[q] = v * SC;
      }
      #pragma unroll
      for (int kb = 0; kb < 4; ++kb) {
        half8 ah = *(const half8*)(nAh + ((kb << 6) + lane) * 8);
        half8 al = *(const half8*)(nAl + ((kb << 6) + lane) * 8);
        half8 bh = *(const half8*)(Wh + ((c * 4 + kb) * 64 + lane) * 8);
        half8 bl = *(const half8*)(Wl + ((c * 4 + kb) * 64 + lane) * 8);
        acc = __builtin_amdgcn_mfma_f32_16x16x32_f16(ah, bh, acc, 0, 0, 0);
        acc = __builtin_amdgcn_mfma_f32_16x16x32_f16(ah, bl, acc, 0, 0, 0);
        acc = __builtin_amdgcn_mfma_f32_16x16x32_f16(al, bh, acc, 0, 0, 0);
      }
      #pragma unroll
      for (int q = 0; q < 4; ++q)
        X[row0 + q][col] = fmaxf(acc[q] * 1024.f, 0.f);
    }
    __syncthreads();
  };

  const half_t* nh1 = wsp + 2 * 16384;  const half_t* nl1 = nh1 + 16384;
  const half_t* nh2 = wsp + 4 * 16384;  const half_t* nl2 = nh2 + 16384;
  const half_t* dh1 = wsp + 6 * 16384;  const half_t* dl1 = dh1 + 16384;
  const half_t* dh2 = wsp + 8 * 16384;  const half_t* dl2 = dh2 + 16384;

  layerM(nh1, nl1, nb1, false);   // node mlp 1
  layerM(nh2, nl2, nb2, false);   // node mlp 2
  layerM(dh1, dl1, db1, true);    // dec 1 (P part via dw1 rows 0..3)
  layerM(dh2, dl2, db2, false);   // dec 2

  // output head: nxt = X @ ow + ob + prev
  {
    int ln = tid >> 4, d = (tid >> 2) & 3, kq = tid & 3;
    float cs = 0.f;
    #pragma unroll
    for (int i = 0; i < 32; ++i) {
      int k = (kq << 5) + i;
      cs = fmaf(X[ln][k], ow[k * 4 + d], cs);
    }
    cs += __shfl_xor(cs, 1, 64);
    cs += __shfl_xor(cs, 2, 64);
    if ((tid & 3) == 0) {
      float a = cs + ob[d] + sP[ln][d];
      int n = t0 + ln, gid = b * 64 + n;
      win[gid * WROW + (step + 5) * 4 + d] = a;
      out[((b * 8 + step) * 64 + n) * 4 + d] = a;
      s_nxt[ln][d] = a;
    }
  }
  __syncthreads();

  if (step < 7) {
    int ln = tid >> 4, lane2 = tid & 15;
    int gid = b * 64 + t0 + ln;
    float* mycp = cp + ln * 160;
    mycp[lane2] = win[gid * WROW + (step + 1) * 4 + lane2];
    if (lane2 < 4) mycp[16 + lane2] = s_nxt[ln][lane2];
    __syncthreads();
    conv_proj<16>(lane2, gid, mycp, cw1, cb1, cw2, cb2, ew1, anW, bnW);
  }
}

extern "C" void kernel_launch(void* const* d_in, const int* in_sizes, int n_in,
                              void* d_out, int out_size, void* d_ws, size_t ws_size,
                              hipStream_t stream) {
  (void)in_sizes; (void)n_in; (void)out_size; (void)ws_size;
  const float* ts  = (const float*)d_in[0];
  const float* cw1 = (const float*)d_in[1];
  const float* cb1 = (const float*)d_in[2];
  const float* cw2 = (const float*)d_in[3];
  const float* cb2 = (const float*)d_in[4];
  const float* ew1 = (const float*)d_in[5];
  const float* eb1 = (const float*)d_in[6];
  const float* ew2 = (const float*)d_in[7];
  const float* eb2 = (const float*)d_in[8];
  const float* nw1 = (const float*)d_in[9];
  const float* nb1 = (const float*)d_in[10];
  const float* nw2 = (const float*)d_in[11];
  const float* nb2 = (const float*)d_in[12];
  const float* dw1 = (const float*)d_in[13];
  const float* db1 = (const float*)d_in[14];
  const float* dw2 = (const float*)d_in[15];
  const float* db2 = (const float*)d_in[16];
  const float* ow  = (const float*)d_in[17];
  const float* ob  = (const float*)d_in[18];
  float* out = (float*)d_out;
  float* ws  = (float*)d_ws;
  float* win = ws;                        // 425984 floats
  float* an0 = win + 425984;              // 1048576
  float* bn0 = an0 + 1048576;             // 1048576
  float* an1 = bn0 + 1048576;             // 1048576
  float* bn1 = an1 + 1048576;             // 1048576
  half_t* wsp = (half_t*)(bn1 + 1048576); // 10 x 16384 halves

  hipLaunchKernelGGL(k_wsplit, dim3(320), dim3(256), 0, stream,
                     ew2, nw1, nw2, dw1, dw2, wsp);
  hipLaunchKernelGGL(k_init, dim3(512), dim3(256), 0, stream,
                     ts, cw1, cb1, cw2, cb2, ew1, win, an0, bn0);
  for (int k = 0; k < 8; ++k) {
    const float* anR = (k & 1) ? an1 : an0;
    const float* bnR = (k & 1) ? bn1 : bn0;
    float* anW = (k & 1) ? an0 : an1;
    float* bnW = (k & 1) ? bn0 : bn1;
    hipLaunchKernelGGL(k_step, dim3(512), dim3(256), 0, stream,
                       k, anR, bnR, anW, bnW, eb1, eb2, wsp,
                       nb1, nb2, dw1, db1, db2, ow, ob,
                       cw1, cb1, cw2, cb2, ew1, win, out);
  }
}